// Round 8
// baseline (745.062 us; speedup 1.0000x reference)
//
#include <hip/hip_runtime.h>
#include <hip/hip_bf16.h>
#include <stdint.h>

#define DD 768
#define EE 8
#define HHID 3072
#define NTOK 8192
#define CAP 16384
#define HROWS 3072

typedef __attribute__((ext_vector_type(8))) short bshort8;
typedef __attribute__((ext_vector_type(4))) float f32x4;

typedef __attribute__((address_space(1))) const unsigned int g_u32;
typedef __attribute__((address_space(3))) unsigned int l_u32;

__device__ __forceinline__ void glds16(const void* g, void* l) {
    __builtin_amdgcn_global_load_lds((g_u32*)g, (l_u32*)l, 16, 0, 0);
}

__device__ __forceinline__ unsigned short f2bf(float f) {
    unsigned int u = __float_as_uint(f);
    u += 0x7fffu + ((u >> 16) & 1u);   // round-to-nearest-even
    return (unsigned short)(u >> 16);
}

// ---------------- Router scores: noisy top-2, NO atomics ----------------
__global__ __launch_bounds__(256) void router_score(
    const float* __restrict__ x, const float* __restrict__ noise,
    const float* __restrict__ w_route, const float* __restrict__ b_route,
    const float* __restrict__ w_noise, const float* __restrict__ b_noise,
    int2* __restrict__ eidx, float2* __restrict__ gates,
    unsigned short* __restrict__ xbf)
{
    const int lane = threadIdx.x & 63;
    const int wv = threadIdx.x >> 6;
    const int t = blockIdx.x * 4 + wv;

    float aR[EE], aN[EE];
#pragma unroll
    for (int e = 0; e < EE; ++e) { aR[e] = 0.f; aN[e] = 0.f; }

    const float* xr = x + (size_t)t * DD;
    unsigned short* xb = xbf + (size_t)t * DD;
#pragma unroll 4
    for (int d = lane; d < DD; d += 64) {
        float xv = xr[d];
        xb[d] = f2bf(xv);                         // merged xconv
        const float4* wr = reinterpret_cast<const float4*>(w_route + d * EE);
        const float4* wn = reinterpret_cast<const float4*>(w_noise + d * EE);
        float4 r0 = wr[0], r1 = wr[1];
        float4 n0 = wn[0], n1 = wn[1];
        aR[0] += xv * r0.x; aR[1] += xv * r0.y; aR[2] += xv * r0.z; aR[3] += xv * r0.w;
        aR[4] += xv * r1.x; aR[5] += xv * r1.y; aR[6] += xv * r1.z; aR[7] += xv * r1.w;
        aN[0] += xv * n0.x; aN[1] += xv * n0.y; aN[2] += xv * n0.z; aN[3] += xv * n0.w;
        aN[4] += xv * n1.x; aN[5] += xv * n1.y; aN[6] += xv * n1.z; aN[7] += xv * n1.w;
    }
#pragma unroll
    for (int e = 0; e < EE; ++e) {
#pragma unroll
        for (int off = 32; off > 0; off >>= 1) {
            aR[e] += __shfl_xor(aR[e], off);
            aN[e] += __shfl_xor(aN[e], off);
        }
    }

    if (lane == 0) {
        float nv[EE];
#pragma unroll
        for (int e = 0; e < EE; ++e) {
            float z = aN[e] + b_noise[e];
            float sp = (z > 20.f) ? z : log1pf(expf(z));     // softplus
            nv[e] = aR[e] + b_route[e] + noise[(size_t)t * EE + e] * sp;
        }
        int e1 = 0; float v1 = nv[0];
#pragma unroll
        for (int e = 1; e < EE; ++e) if (nv[e] > v1) { v1 = nv[e]; e1 = e; }
        int e2 = -1; float v2 = 0.f;
#pragma unroll
        for (int e = 0; e < EE; ++e) {
            if (e == e1) continue;
            if (e2 < 0 || nv[e] > v2) { v2 = nv[e]; e2 = e; }
        }
        float ex = expf(v2 - v1);
        float inv = 1.f / (1.f + ex);
        int2 ee; ee.x = e1; ee.y = e2;
        float2 gg; gg.x = inv; gg.y = ex * inv;
        eidx[t] = ee;
        gates[t] = gg;
    }
}

// ---------------- Scatter: build per-expert compact lists ----------------
__global__ __launch_bounds__(1024) void scatter_kernel(
    const int2* __restrict__ eidx, const float2* __restrict__ gates,
    int* __restrict__ cnt, int* __restrict__ tlist, float* __restrict__ glist)
{
    __shared__ int lcnt[EE];
    const int tid = threadIdx.x;
    if (tid < EE) lcnt[tid] = 0;
    __syncthreads();
    const int lane = tid & 63;
    const int wv = tid >> 6;
    const unsigned long long lowmask = (1ull << lane) - 1ull;

    for (int it = 0; it < NTOK / 1024; ++it) {
        int t = it * 1024 + wv * 64 + lane;
        int2 ee = eidx[t];
        float2 gg = gates[t];
#pragma unroll
        for (int e = 0; e < EE; ++e) {
            unsigned long long m1 = __ballot(ee.x == e);
            unsigned long long m2 = __ballot(ee.y == e);
            int c1 = __popcll(m1);
            int c2 = __popcll(m2);
            int base = 0;
            if (lane == 0 && (c1 + c2) > 0) base = atomicAdd(&lcnt[e], c1 + c2);
            base = __shfl(base, 0);
            if (ee.x == e) {
                int pos = base + __popcll(m1 & lowmask);
                tlist[e * CAP + pos] = t; glist[e * CAP + pos] = gg.x;
            }
            if (ee.y == e) {
                int pos = base + c1 + __popcll(m2 & lowmask);
                tlist[e * CAP + pos] = t; glist[e * CAP + pos] = gg.y;
            }
        }
    }
    __syncthreads();
    if (tid < EE) cnt[tid] = lcnt[tid];
}

// ---------------- Weight convert+transpose: fp32 [R][C] -> bf16 [C][R] ----------------
__global__ __launch_bounds__(256) void wconv_kernel(
    const float* __restrict__ W1, const float* __restrict__ W2,
    unsigned short* __restrict__ W1T, unsigned short* __restrict__ W2T)
{
    __shared__ unsigned short t2[64][80];
    const int bid = blockIdx.x;
    const int mat = bid / 1152;          // expert
    const int r0 = bid % 1152;
    const float* src; unsigned short* dst; int R, C, tr, tc;
    if (r0 < 576) {                      // W1[e]: [768][3072] -> W1T[e]: [3072][768]
        src = W1 + (size_t)mat * DD * HHID; dst = W1T + (size_t)mat * DD * HHID;
        R = DD; C = HHID; tr = r0 / 48; tc = r0 % 48;
    } else {                             // W2[e]: [3072][768] -> W2T[e]: [768][3072]
        int r1 = r0 - 576;
        src = W2 + (size_t)mat * DD * HHID; dst = W2T + (size_t)mat * DD * HHID;
        R = HHID; C = DD; tr = r1 / 12; tc = r1 % 12;
    }
    const int tid = threadIdx.x;
    {
        const int r = tid >> 2;
        const int c0 = (tid & 3) * 16;
        const float* srow = src + (size_t)(tr * 64 + r) * C + tc * 64 + c0;
#pragma unroll
        for (int j = 0; j < 16; j += 4) {
            float4 v = *reinterpret_cast<const float4*>(srow + j);
            t2[c0 + j + 0][r] = f2bf(v.x);
            t2[c0 + j + 1][r] = f2bf(v.y);
            t2[c0 + j + 2][r] = f2bf(v.z);
            t2[c0 + j + 3][r] = f2bf(v.w);
        }
    }
    __syncthreads();
    {
        const int c = tid >> 2;
        const int ch = (tid & 3) * 16;
        unsigned short* drow = dst + (size_t)(tc * 64 + c) * R + tr * 64 + ch;
#pragma unroll
        for (int j = 0; j < 16; j += 8)
            *reinterpret_cast<uint4*>(drow + j) = *reinterpret_cast<const uint4*>(&t2[c][ch + j]);
    }
}

// =====================================================================
// Shared GEMM machinery: BM=256, BN=128, BK=64, 8 waves (2m x 4n),
// 3-buffer LDS (144 KiB), depth-2 prefetch, counted vmcnt(6), setprio.
// Swizzle: LDS linear dest; global src chunk ^= row&7; ds_read chunk ^= row&7.
// =====================================================================
#define SA_(buf, i) { glds16(pa[i], &As[buf][(i) * 4096 + w * 512]); pa[i] += 128; }
#define SB_(buf, j) { glds16(pb[j], &Bs[buf][(j) * 4096 + w * 512]); pb[j] += 128; }
#define PH_(buf, P) { \
    const char* Ab = (const char*)As[buf]; \
    const char* Bb = (const char*)Bs[buf]; \
    _Pragma("unroll") \
    for (int s = 0; s < 2; ++s) { \
        bshort8 af[4], bfr[2]; \
        _Pragma("unroll") \
        for (int mfl = 0; mfl < 4; ++mfl) { \
            int row = wm * 128 + ((P) * 4 + mfl) * 16 + r15; \
            af[mfl] = *(const bshort8*)(Ab + row * 128 + (((s * 4 + kq) ^ (row & 7)) << 4)); \
        } \
        _Pragma("unroll") \
        for (int nf = 0; nf < 2; ++nf) { \
            int row = wn * 32 + nf * 16 + r15; \
            bfr[nf] = *(const bshort8*)(Bb + row * 128 + (((s * 4 + kq) ^ (row & 7)) << 4)); \
        } \
        __builtin_amdgcn_s_setprio(1); \
        _Pragma("unroll") \
        for (int mfl = 0; mfl < 4; ++mfl) \
            _Pragma("unroll") \
            for (int nf = 0; nf < 2; ++nf) \
                acc[(P) * 4 + mfl][nf] = __builtin_amdgcn_mfma_f32_16x16x32_bf16(af[mfl], bfr[nf], acc[(P) * 4 + mfl][nf], 0, 0, 0); \
        __builtin_amdgcn_s_setprio(0); \
    } }

#define GEMM_LOOP(NKv) \
    SA_(0, 0) SA_(0, 1) SA_(0, 2) SA_(0, 3) SB_(0, 0) SB_(0, 1) \
    SA_(1, 0) SA_(1, 1) SA_(1, 2) SA_(1, 3) SB_(1, 0) SB_(1, 1) \
    asm volatile("s_waitcnt vmcnt(6)" ::: "memory"); \
    __builtin_amdgcn_s_barrier(); \
    { int bc = 0, bs = 2; \
    _Pragma("unroll 1") \
    for (int kt = 0; kt < (NKv); ++kt) { \
        int st = (kt + 2) < (NKv); \
        if (st) { SA_(bs, 0) SA_(bs, 1) SA_(bs, 2) } \
        PH_(bc, 0); \
        __builtin_amdgcn_s_barrier(); \
        if (st) { SA_(bs, 3) SB_(bs, 0) SB_(bs, 1) } \
        PH_(bc, 1); \
        if (kt + 2 < (NKv))      { asm volatile("s_waitcnt vmcnt(6)" ::: "memory"); } \
        else if (kt + 1 < (NKv)) { asm volatile("s_waitcnt vmcnt(0)" ::: "memory"); } \
        __builtin_amdgcn_s_barrier(); \
        bc = bc == 2 ? 0 : bc + 1; \
        bs = bs == 2 ? 0 : bs + 1; \
    } }

// GEMM1: h[e][slot][hcol] = relu( gather(xbf) @ W1T[e] + b1[e] ), bf16 out
__global__ __launch_bounds__(512, 2) void gemm1_kernel(
    const unsigned short* __restrict__ xbf,   // [NTOK][768]
    const unsigned short* __restrict__ W1T,   // [E][3072][768]
    const float* __restrict__ b1,             // [E][3072]
    const int* __restrict__ cnt, const int* __restrict__ tlist,
    unsigned short* __restrict__ hbuf,        // [E][HROWS][hpass]
    int hp0, int hpass)
{
    __shared__ __align__(16) unsigned short As[3][256 * 64];  // 96 KiB
    __shared__ __align__(16) unsigned short Bs[3][128 * 64];  // 48 KiB

    const int e = blockIdx.x & 7;
    const int tile = blockIdx.x >> 3;
    const int mt = tile % 12;
    const int nt = tile / 12;
    int n = cnt[e]; n = n < HROWS ? n : HROWS;
    const int mbase = mt * 256;
    if (mbase >= n) return;
    const int nbase = nt * 128;

    const int tid = threadIdx.x;
    const int lane = tid & 63;
    const int w = tid >> 6;
    const int rl = tid >> 3;
    const int ch = tid & 7;

    const char* pa[4]; const char* pb[2];
#pragma unroll
    for (int i = 0; i < 4; ++i) {
        int r = i * 64 + rl;
        int slot = mbase + r;
        int cs = slot < n ? slot : n - 1;
        int tok = tlist[e * CAP + cs];
        pa[i] = (const char*)xbf + (size_t)tok * 1536 + ((ch ^ (r & 7)) << 4);
    }
#pragma unroll
    for (int j = 0; j < 2; ++j) {
        int r = j * 64 + rl;
        int hcol = hp0 + nbase + r;
        pb[j] = (const char*)W1T + ((size_t)(e * HHID + hcol)) * 1536 + ((ch ^ (r & 7)) << 4);
    }

    const int wm = w & 1;
    const int wn = w >> 1;
    const int r15 = lane & 15;
    const int kq = lane >> 4;

    f32x4 acc[8][2];
#pragma unroll
    for (int mf = 0; mf < 8; ++mf)
#pragma unroll
        for (int nf = 0; nf < 2; ++nf)
            acc[mf][nf] = (f32x4)0.f;

    GEMM_LOOP(12)

    // epilogue: relu(acc + b1) -> hbuf bf16
#pragma unroll
    for (int nf = 0; nf < 2; ++nf) {
        int col = nbase + wn * 32 + nf * 16 + r15;
        float bb = b1[e * HHID + hp0 + col];
#pragma unroll
        for (int mf = 0; mf < 8; ++mf) {
            int rowb = mbase + wm * 128 + mf * 16 + kq * 4;
#pragma unroll
            for (int rr = 0; rr < 4; ++rr) {
                float v = fmaxf(acc[mf][nf][rr] + bb, 0.f);
                hbuf[((size_t)(e * HROWS + rowb + rr)) * hpass + col] = f2bf(v);
            }
        }
    }
}

// GEMM2: out[token] += gate * ( h @ W2T[e] + b2[e] ), fp32 atomics
__global__ __launch_bounds__(512, 2) void gemm2_kernel(
    const unsigned short* __restrict__ hbuf,  // [E][HROWS][hpass]
    const unsigned short* __restrict__ W2T,   // [E][768][3072]
    const float* __restrict__ b2,             // [E][768]
    const int* __restrict__ cnt, const int* __restrict__ tlist,
    const float* __restrict__ glist, float* __restrict__ out,
    int hp0, int hpass, int addb2)
{
    __shared__ __align__(16) unsigned short As[3][256 * 64];
    __shared__ __align__(16) unsigned short Bs[3][128 * 64];

    const int e = blockIdx.x & 7;
    const int tile = blockIdx.x >> 3;
    const int mt = tile % 12;
    const int nt = tile / 12;                 // 0..5
    int n = cnt[e]; n = n < HROWS ? n : HROWS;
    const int mbase = mt * 256;
    if (mbase >= n) return;
    const int nbase = nt * 128;

    const int tid = threadIdx.x;
    const int lane = tid & 63;
    const int w = tid >> 6;
    const int rl = tid >> 3;
    const int ch = tid & 7;
    const size_t hrow_b = (size_t)hpass * 2;

    const char* pa[4]; const char* pb[2];
#pragma unroll
    for (int i = 0; i < 4; ++i) {
        int r = i * 64 + rl;
        pa[i] = (const char*)hbuf + (size_t)(e * HROWS + mbase + r) * hrow_b + ((ch ^ (r & 7)) << 4);
    }
#pragma unroll
    for (int j = 0; j < 2; ++j) {
        int r = j * 64 + rl;
        int d = nbase + r;
        pb[j] = (const char*)W2T + ((size_t)(e * DD + d)) * 6144 + (size_t)hp0 * 2 + ((ch ^ (r & 7)) << 4);
    }

    const int wm = w & 1;
    const int wn = w >> 1;
    const int r15 = lane & 15;
    const int kq = lane >> 4;

    f32x4 acc[8][2];
#pragma unroll
    for (int mf = 0; mf < 8; ++mf)
#pragma unroll
        for (int nf = 0; nf < 2; ++nf)
            acc[mf][nf] = (f32x4)0.f;

    const int NK = hpass >> 6;
    GEMM_LOOP(NK)

    // epilogue: atomic scatter gate*(y [+ b2])
    float bb[2];
#pragma unroll
    for (int nf = 0; nf < 2; ++nf) {
        int d = nbase + wn * 32 + nf * 16 + r15;
        bb[nf] = addb2 ? b2[e * DD + d] : 0.f;
    }
#pragma unroll
    for (int mf = 0; mf < 8; ++mf) {
#pragma unroll
        for (int rr = 0; rr < 4; ++rr) {
            int slot = mbase + wm * 128 + mf * 16 + kq * 4 + rr;
            if (slot < n) {
                int tok = tlist[e * CAP + slot];
                float g = glist[e * CAP + slot];
                float* orow = out + (size_t)tok * DD;
#pragma unroll
                for (int nf = 0; nf < 2; ++nf) {
                    int d = nbase + wn * 32 + nf * 16 + r15;
                    atomicAdd(orow + d, g * (acc[mf][nf][rr] + bb[nf]));
                }
            }
        }
    }
}

extern "C" void kernel_launch(void* const* d_in, const int* in_sizes, int n_in,
                              void* d_out, int out_size, void* d_ws, size_t ws_size,
                              hipStream_t stream) {
    const float* x       = (const float*)d_in[0];
    const float* noise   = (const float*)d_in[1];
    const float* w_route = (const float*)d_in[2];
    const float* b_route = (const float*)d_in[3];
    const float* w_noise = (const float*)d_in[4];
    const float* b_noise = (const float*)d_in[5];
    const float* W1      = (const float*)d_in[6];
    const float* b1      = (const float*)d_in[7];
    const float* W2      = (const float*)d_in[8];
    const float* b2      = (const float*)d_in[9];
    float* out = (float*)d_out;

    char* ws = (char*)d_ws;
    int*    cnt   = (int*)ws;                                   // 1 KB
    int*    tlist = (int*)(ws + 1024);
    float*  glist = (float*)(ws + 1024 + (size_t)CAP * EE * 4);
    int2*   eidx  = (int2*)(ws + 1024 + (size_t)CAP * EE * 8);
    float2* gates = (float2*)(ws + 1024 + (size_t)CAP * EE * 8 + (size_t)NTOK * 8);

    const size_t OFF_W1T = (size_t)2 << 20;
    const size_t SZ_W    = (size_t)EE * DD * HHID * 2;
    const size_t OFF_W2T = OFF_W1T + SZ_W;
    const size_t OFF_XBF = OFF_W2T + SZ_W;
    const size_t SZ_XBF  = (size_t)NTOK * DD * 2;
    const size_t OFF_HB  = OFF_XBF + SZ_XBF;
    unsigned short* W1T = (unsigned short*)(ws + OFF_W1T);
    unsigned short* W2T = (unsigned short*)(ws + OFF_W2T);
    unsigned short* xbf = (unsigned short*)(ws + OFF_XBF);
    unsigned short* hbuf = (unsigned short*)(ws + OFF_HB);

    const size_t HB_FULL = (size_t)EE * HROWS * HHID * 2;
    size_t hav = (ws_size > OFF_HB) ? ws_size - OFF_HB : 0;
    int npass = 0;
    if      (hav >= HB_FULL)      npass = 1;
    else if (hav >= HB_FULL / 2)  npass = 2;
    else if (hav >= HB_FULL / 4)  npass = 4;
    else if (hav >= HB_FULL / 8)  npass = 8;
    else                          npass = 12;

    hipMemsetAsync(d_out, 0, (size_t)out_size * sizeof(float), stream);

    router_score<<<NTOK / 4, 256, 0, stream>>>(x, noise, w_route, b_route,
                                               w_noise, b_noise, eidx, gates, xbf);
    scatter_kernel<<<1, 1024, 0, stream>>>(eidx, gates, cnt, tlist, glist);
    wconv_kernel<<<EE * 1152, 256, 0, stream>>>(W1, W2, W1T, W2T);

    const int hpass = HHID / npass;
    for (int p = 0; p < npass; ++p) {
        gemm1_kernel<<<12 * (hpass / 128) * 8, 512, 0, stream>>>(
            xbf, W1T, b1, cnt, tlist, hbuf, p * hpass, hpass);
        gemm2_kernel<<<12 * 6 * 8, 512, 0, stream>>>(
            hbuf, W2T, b2, cnt, tlist, glist, out, p * hpass, hpass, p == 0 ? 1 : 0);
    }
}